// Round 8
// baseline (807.677 us; speedup 1.0000x reference)
//
#include <hip/hip_runtime.h>
#include <hip/hip_bf16.h>
#include <stdint.h>

// ---------------------------------------------------------------------------
// QuantGRU: T=512, B=64, I=256, H=256. ACT scale 2^-7, W scale 2^-8.
// Fully exact integer arithmetic; sigmoid/tanh via 256-entry f64-built LUTs.
// Recurrence (R8): TWO independent batches per block, interleaved in each
// thread -- their serial chains (LDS round-trip, LUT gathers, dot chains)
// overlap, and the 3 weight columns per thread are shared across both.
// ---------------------------------------------------------------------------

#define T_STEPS 512
#define BATCH   64
#define IDIM    256
#define HDIM    256
#define N3H     768   // 3*H

#if defined(__has_builtin)
#if __has_builtin(__builtin_amdgcn_sdot4)
#define DOT4(a,b,c) __builtin_amdgcn_sdot4((int)(a),(int)(b),(int)(c),false)
#endif
#endif
#ifndef DOT4
__device__ __forceinline__ int dot4_sw(uint32_t a, uint32_t b, int c){
  c += (int)(int8_t)(a)      * (int)(int8_t)(b);
  c += (int)(int8_t)(a>>8)   * (int)(int8_t)(b>>8);
  c += (int)(int8_t)(a>>16)  * (int)(int8_t)(b>>16);
  c += (int)(int8_t)(a>>24)  * (int)(int8_t)(b>>24);
  return c;
}
#define DOT4(a,b,c) dot4_sw((uint32_t)(a),(uint32_t)(b),(int)(c))
#endif

// select dword component of a uint4 by compile-time constant (stays in VGPRs)
#define CHUNK(W,c) (((c)&3)==0 ? W[(c)>>2].x : ((c)&3)==1 ? W[(c)>>2].y : \
                    ((c)&3)==2 ? W[(c)>>2].z : W[(c)>>2].w)

// LDS-only workgroup barrier (no vmcnt drain; loads/stores stay in flight)
__device__ __forceinline__ void barrier_lds() {
  asm volatile("s_waitcnt lgkmcnt(0)\n\ts_barrier" ::: "memory");
}

// ---- exact integer round-to-nearest-even helpers (verified vs jnp.round) ---
__device__ __forceinline__ int clamp8(int x)   { return min(127, max(-128, x)); }
__device__ __forceinline__ int rne_half(int y) { int t = y >> 1; return t + (t & y & 1); }
__device__ __forceinline__ int rne_s8(int s)   { return (s + 127 + ((s >> 8) & 1)) >> 8; }
__device__ __forceinline__ int rne_s7(int p)   { return (p + 63 + ((p >> 7) & 1)) >> 7; }

// float RNE+clamp (quantize; used in prep/gemm only)
__device__ __forceinline__ int rneclamp(float v) {
  int q = (int)rintf(v);
  return min(127, max(-128, q));
}

__device__ __forceinline__ uint32_t packq4(float4 f, float sc) {
  uint32_t b0 = (uint32_t)(uint8_t)(int8_t)rneclamp(f.x * sc);
  uint32_t b1 = (uint32_t)(uint8_t)(int8_t)rneclamp(f.y * sc);
  uint32_t b2 = (uint32_t)(uint8_t)(int8_t)rneclamp(f.z * sc);
  uint32_t b3 = (uint32_t)(uint8_t)(int8_t)rneclamp(f.w * sc);
  return b0 | (b1 << 8) | (b2 << 16) | (b3 << 24);
}

// ---------------------------------------------------------------------------
// prep: W -> k-chunk-transposed int8 (for gemm_wx coalesced column loads),
// R -> plain column-major int8, biases -> int8.
// ---------------------------------------------------------------------------
__global__ void prep_kernel(const float* __restrict__ W, const float* __restrict__ R,
                            const float* __restrict__ bx, const float* __restrict__ br,
                            int8_t* __restrict__ Wq, int8_t* __restrict__ Rq,
                            int8_t* __restrict__ bx8, int8_t* __restrict__ br8) {
  const int NW = IDIM * N3H; // 196608
  int idx = blockIdx.x * 256 + threadIdx.x;
  if (idx < NW) {
    int k = idx / N3H, j = idx % N3H;
    Wq[((size_t)(k >> 4) * N3H + j) * 16 + (k & 15)] = (int8_t)rneclamp(W[idx] * 256.0f);
  } else if (idx < 2 * NW) {
    int i2 = idx - NW;
    int k = i2 / N3H, j = i2 % N3H;
    Rq[(size_t)j * HDIM + k] = (int8_t)rneclamp(R[i2] * 256.0f);   // col-major
  } else if (idx < 2 * NW + N3H) {
    int i2 = idx - 2 * NW;
    bx8[i2] = (int8_t)rneclamp(bx[i2] * 256.0f);
  } else if (idx < 2 * NW + 2 * N3H) {
    int i2 = idx - 2 * NW - N3H;
    br8[i2] = (int8_t)rneclamp(br[i2] * 256.0f);
  }
}

// ---------------------------------------------------------------------------
// gemm_wx: Wx_q[b][t][j] = clamp(rne( (fq(x) . Wq col j) / 256 ))  (int8)
// one block per t (64 rows), 768 threads = one per output column.
// ---------------------------------------------------------------------------
__global__ __launch_bounds__(768, 1) void gemm_wx_kernel(
    const float* __restrict__ x, const int8_t* __restrict__ Wq,
    int8_t* __restrict__ WxQ8) {
  const int t = blockIdx.x;   // 0..511
  const int j = threadIdx.x;  // 0..767

  __shared__ uint4 xq4[64 * 16];   // 64 rows x 256 int8 = 16KB
  uint32_t* xq = (uint32_t*)xq4;

  uint4 w[16];
  const uint4* wp = (const uint4*)Wq;
  #pragma unroll
  for (int kk = 0; kk < 16; ++kk) w[kk] = wp[kk * N3H + j];

  const float4* xg = (const float4*)(x) + (size_t)t * 4096;
  for (int i = j; i < 4096; i += 768) {
    float4 f = xg[i];
    xq[i] = packq4(f, 128.0f);
  }
  __syncthreads();

  for (int r = 0; r < 64; ++r) {
    int s = 0;
    #pragma unroll
    for (int kk = 0; kk < 16; ++kk) {
      uint4 hv = xq4[r * 16 + kk];
      s = DOT4(hv.x, w[kk].x, s);
      s = DOT4(hv.y, w[kk].y, s);
      s = DOT4(hv.z, w[kk].z, s);
      s = DOT4(hv.w, w[kk].w, s);
    }
    int q = clamp8(rne_s8(s));
    WxQ8[((size_t)r * T_STEPS + t) * N3H + j] = (int8_t)q;
  }
}

// ---------------------------------------------------------------------------
// gru_rec8: one block per PAIR of batch elements; 256 threads (4 waves).
// Thread j owns h[j] and gate-triple columns {j, j+256, j+512} of R for BOTH
// batches; the two recurrences interleave so latency chains overlap.
// ---------------------------------------------------------------------------
__global__ __launch_bounds__(256, 1)
void gru_rec8_kernel(
    const float* __restrict__ h0, const int8_t* __restrict__ Rq,
    const int8_t* __restrict__ bx8, const int8_t* __restrict__ br8,
    const int8_t* __restrict__ WxQ8, float* __restrict__ out) {
  const int bA = blockIdx.x * 2;      // batch pair
  const int bB = bA + 1;
  const int j = threadIdx.x;          // 0..255
  const int lane = j & 63;

  __shared__ uint32_t hqA[2][64];     // double-buffered int8 h, batch A
  __shared__ uint32_t hqB[2][64];     // batch B
  __shared__ int8_t lutS[256];
  __shared__ int8_t lutT[256];

  // R columns j, j+256, j+512 (shared by both batches): 48 uint4
  uint4 wz[16], wr[16], wg[16];
  {
    const uint4* pz = (const uint4*)(Rq + (size_t)j * HDIM);
    const uint4* pr = (const uint4*)(Rq + (size_t)(j + 256) * HDIM);
    const uint4* pg = (const uint4*)(Rq + (size_t)(j + 512) * HDIM);
    #pragma unroll
    for (int kk = 0; kk < 16; ++kk) { wz[kk] = pz[kk]; wr[kk] = pr[kk]; wg[kk] = pg[kk]; }
  }
  const int bz  = (int)bx8[j];
  const int brg = (int)bx8[j + 256];
  const int bg  = (int)bx8[j + 512];
  const int vbz = (int)br8[j];
  const int vbr = (int)br8[j + 256];
  const int vbg = (int)br8[j + 512];

  // LUTs in f64 (inputs are fq-clamped to k/128, k in [-128,127])
  {
    double a = ((double)j - 128.0) / 128.0;
    lutS[j] = (int8_t)min(127, max(-128, (int)rint(128.0 / (1.0 + exp(-a)))));
    lutT[j] = (int8_t)min(127, max(-128, (int)rint(128.0 * tanh(a))));
  }
  // h carried as exact integers (units 1/128)
  int hiA = (int)rintf(h0[bA * HDIM + j] * 128.0f);
  int hiB = (int)rintf(h0[bB * HDIM + j] * 128.0f);
  ((int8_t*)&hqA[0][0])[j] = (int8_t)clamp8(hiA);
  ((int8_t*)&hqB[0][0])[j] = (int8_t)clamp8(hiB);
  __syncthreads();

  const int8_t* wxpA = WxQ8 + (size_t)bA * T_STEPS * N3H + j;
  const int8_t* wxpB = WxQ8 + (size_t)bB * T_STEPS * N3H + j;
  float* outpA = out + (size_t)bA * HDIM + j;
  float* outpB = out + (size_t)bB * HDIM + j;

  // Wx 2-deep prefetch pipeline per batch
  int wxA0 = (int)wxpA[0],   wxA1 = (int)wxpA[256],       wxA2 = (int)wxpA[512];
  int wxA0n = (int)wxpA[N3H], wxA1n = (int)wxpA[N3H + 256], wxA2n = (int)wxpA[N3H + 512];
  int wxB0 = (int)wxpB[0],   wxB1 = (int)wxpB[256],       wxB2 = (int)wxpB[512];
  int wxB0n = (int)wxpB[N3H], wxB1n = (int)wxpB[N3H + 256], wxB2n = (int)wxpB[N3H + 512];

  for (int t = 0; t < T_STEPS; ++t) {
    const int cur = t & 1, nxt = cur ^ 1;

    // issue Wx loads for t+2 first (~2 steps of latency hiding)
    const int8_t* pA = wxpA + (size_t)min(t + 2, T_STEPS - 1) * N3H;
    const int8_t* pB = wxpB + (size_t)min(t + 2, T_STEPS - 1) * N3H;
    int nzA = (int)pA[0], nrA = (int)pA[256], ngA = (int)pA[512];
    int nzB = (int)pB[0], nrB = (int)pB[256], ngB = (int)pB[512];

    // ---- GEMV for BOTH batches, interleaved (weights shared) ----
    uint32_t hwA = hqA[cur][lane];
    uint32_t hwB = hqB[cur][lane];
    int szA = 0, srA = 0, sgA = 0, szB = 0, srB = 0, sgB = 0;
    #pragma unroll
    for (int c = 0; c < 64; ++c) {
      int ha = __builtin_amdgcn_readlane((int)hwA, c);
      int hb = __builtin_amdgcn_readlane((int)hwB, c);
      szA = DOT4(ha, CHUNK(wz, c), szA);
      szB = DOT4(hb, CHUNK(wz, c), szB);
      srA = DOT4(ha, CHUNK(wr, c), srA);
      srB = DOT4(hb, CHUNK(wr, c), srB);
      sgA = DOT4(ha, CHUNK(wg, c), sgA);
      sgB = DOT4(hb, CHUNK(wg, c), sgB);
    }

    // ---- batch A gates (integer, exact) ----
    {
      int vz = clamp8(rne_half(2 * clamp8(rne_s8(szA)) + vbz));
      int vr = clamp8(rne_half(2 * clamp8(rne_s8(srA)) + vbr));
      int vg = clamp8(rne_half(2 * clamp8(rne_s8(sgA)) + vbg));
      int az = clamp8(rne_half(2 * (wxA0 + vz) + bz));
      int zi = (int)lutS[az + 128];
      int ar = clamp8(rne_half(2 * (wxA1 + vr) + brg));
      int ri = (int)lutS[ar + 128];
      int rrh = clamp8(rne_s7(ri * vg));
      int ag = clamp8(rne_half(2 * (wxA2 + rrh) + bg));
      int gi = (int)lutT[ag + 128];
      int oldi = clamp8(rne_s7(zi * hiA));
      int newi = clamp8(rne_s7((128 - zi) * gi));
      hiA = oldi + newi;
      outpA[(size_t)t * BATCH * HDIM] = (float)hiA * (1.0f / 128.0f);
      ((int8_t*)&hqA[nxt][0])[j] = (int8_t)clamp8(hiA);
      wxA0 = wxA0n; wxA1 = wxA1n; wxA2 = wxA2n;
      wxA0n = nzA;  wxA1n = nrA;  wxA2n = ngA;
    }
    // ---- batch B gates (independent; overlaps with A's chain) ----
    {
      int vz = clamp8(rne_half(2 * clamp8(rne_s8(szB)) + vbz));
      int vr = clamp8(rne_half(2 * clamp8(rne_s8(srB)) + vbr));
      int vg = clamp8(rne_half(2 * clamp8(rne_s8(sgB)) + vbg));
      int az = clamp8(rne_half(2 * (wxB0 + vz) + bz));
      int zi = (int)lutS[az + 128];
      int ar = clamp8(rne_half(2 * (wxB1 + vr) + brg));
      int ri = (int)lutS[ar + 128];
      int rrh = clamp8(rne_s7(ri * vg));
      int ag = clamp8(rne_half(2 * (wxB2 + rrh) + bg));
      int gi = (int)lutT[ag + 128];
      int oldi = clamp8(rne_s7(zi * hiB));
      int newi = clamp8(rne_s7((128 - zi) * gi));
      hiB = oldi + newi;
      outpB[(size_t)t * BATCH * HDIM] = (float)hiB * (1.0f / 128.0f);
      ((int8_t*)&hqB[nxt][0])[j] = (int8_t)clamp8(hiB);
      wxB0 = wxB0n; wxB1 = wxB1n; wxB2 = wxB2n;
      wxB0n = nzB;  wxB1n = nrB;  wxB2n = ngB;
    }

    barrier_lds();   // LDS-only: hq[nxt] visible; vmcnt stays in flight
  }
}

// ---------------------------------------------------------------------------
extern "C" void kernel_launch(void* const* d_in, const int* in_sizes, int n_in,
                              void* d_out, int out_size, void* d_ws, size_t ws_size,
                              hipStream_t stream) {
  const float* x  = (const float*)d_in[0];   // (T,B,I)
  const float* h0 = (const float*)d_in[1];   // (B,H)
  const float* W  = (const float*)d_in[2];   // (I,3H)
  const float* R  = (const float*)d_in[3];   // (H,3H)
  const float* bx = (const float*)d_in[4];   // (3H,)
  const float* br = (const float*)d_in[5];   // (3H,)
  float* out = (float*)d_out;                // (T,B,H)

  // workspace layout
  const size_t NW = (size_t)IDIM * N3H;          // 196608
  int8_t* Wq  = (int8_t*)d_ws;                   // 196608
  int8_t* Rq  = Wq + NW;                         // 196608
  int8_t* bx8 = Rq + NW;                         // 768
  int8_t* br8 = bx8 + N3H;                       // 768
  int8_t* WxQ8 = br8 + N3H;                      // 64*512*768 = 25165824

  {
    int total = (int)(2 * NW + 2 * N3H);
    int blocks = (total + 255) / 256;
    prep_kernel<<<blocks, 256, 0, stream>>>(W, R, bx, br, Wq, Rq, bx8, br8);
  }
  gemm_wx_kernel<<<T_STEPS, 768, 0, stream>>>(x, Wq, WxQ8);
  gru_rec8_kernel<<<BATCH / 2, 256, 0, stream>>>(h0, Rq, bx8, br8, WxQ8, out);
}

// Round 10
// 556.445 us; speedup vs baseline: 1.4515x; 1.4515x over previous
//
#include <hip/hip_runtime.h>
#include <hip/hip_bf16.h>
#include <stdint.h>

// ---------------------------------------------------------------------------
// QuantGRU: T=512, B=64, I=256, H=256. ACT scale 2^-7, W scale 2^-8.
// Fully exact integer arithmetic; sigmoid/tanh via 256-entry f64-built LUTs.
// Recurrence (R10): 512 thr/block, ROLE SPLIT so weights fit in arch VGPRs
// (v_dot4 cannot read AGPRs -- R9 proved it). Waves 0-3: z+r columns
// (128 dw/thread) -> zi,ri pre-barrier. Waves 4-7: g column (64 dw/thread,
// proven-resident size) -> gate tail + h update. Two light barriers/step.
// ---------------------------------------------------------------------------

#define T_STEPS 512
#define BATCH   64
#define IDIM    256
#define HDIM    256
#define N3H     768   // 3*H

#if defined(__has_builtin)
#if __has_builtin(__builtin_amdgcn_sdot4)
#define DOT4(a,b,c) __builtin_amdgcn_sdot4((int)(a),(int)(b),(int)(c),false)
#endif
#endif
#ifndef DOT4
__device__ __forceinline__ int dot4_sw(uint32_t a, uint32_t b, int c){
  c += (int)(int8_t)(a)      * (int)(int8_t)(b);
  c += (int)(int8_t)(a>>8)   * (int)(int8_t)(b>>8);
  c += (int)(int8_t)(a>>16)  * (int)(int8_t)(b>>16);
  c += (int)(int8_t)(a>>24)  * (int)(int8_t)(b>>24);
  return c;
}
#define DOT4(a,b,c) dot4_sw((uint32_t)(a),(uint32_t)(b),(int)(c))
#endif

// select dword component of a uint4 by compile-time constant
#define CHUNK(W,c) (((c)&3)==0 ? W[(c)>>2].x : ((c)&3)==1 ? W[(c)>>2].y : \
                    ((c)&3)==2 ? W[(c)>>2].z : W[(c)>>2].w)

// LDS-only workgroup barrier (no vmcnt drain; loads/stores stay in flight)
__device__ __forceinline__ void barrier_lds() {
  asm volatile("s_waitcnt lgkmcnt(0)\n\ts_barrier" ::: "memory");
}

// ---- exact integer round-to-nearest-even helpers (verified vs jnp.round) ---
__device__ __forceinline__ int clamp8(int x)   { return min(127, max(-128, x)); }
__device__ __forceinline__ int rne_half(int y) { int t = y >> 1; return t + (t & y & 1); }
__device__ __forceinline__ int rne_s8(int s)   { return (s + 127 + ((s >> 8) & 1)) >> 8; }
__device__ __forceinline__ int rne_s7(int p)   { return (p + 63 + ((p >> 7) & 1)) >> 7; }

// float RNE+clamp (quantize; used in prep/gemm only)
__device__ __forceinline__ int rneclamp(float v) {
  int q = (int)rintf(v);
  return min(127, max(-128, q));
}

__device__ __forceinline__ uint32_t packq4(float4 f, float sc) {
  uint32_t b0 = (uint32_t)(uint8_t)(int8_t)rneclamp(f.x * sc);
  uint32_t b1 = (uint32_t)(uint8_t)(int8_t)rneclamp(f.y * sc);
  uint32_t b2 = (uint32_t)(uint8_t)(int8_t)rneclamp(f.z * sc);
  uint32_t b3 = (uint32_t)(uint8_t)(int8_t)rneclamp(f.w * sc);
  return b0 | (b1 << 8) | (b2 << 16) | (b3 << 24);
}

// ---------------------------------------------------------------------------
// prep: W -> k-chunk-transposed int8 (for gemm_wx coalesced column loads),
// R -> plain column-major int8, biases -> int8.
// ---------------------------------------------------------------------------
__global__ void prep_kernel(const float* __restrict__ W, const float* __restrict__ R,
                            const float* __restrict__ bx, const float* __restrict__ br,
                            int8_t* __restrict__ Wq, int8_t* __restrict__ Rq,
                            int8_t* __restrict__ bx8, int8_t* __restrict__ br8) {
  const int NW = IDIM * N3H; // 196608
  int idx = blockIdx.x * 256 + threadIdx.x;
  if (idx < NW) {
    int k = idx / N3H, j = idx % N3H;
    Wq[((size_t)(k >> 4) * N3H + j) * 16 + (k & 15)] = (int8_t)rneclamp(W[idx] * 256.0f);
  } else if (idx < 2 * NW) {
    int i2 = idx - NW;
    int k = i2 / N3H, j = i2 % N3H;
    Rq[(size_t)j * HDIM + k] = (int8_t)rneclamp(R[i2] * 256.0f);   // col-major
  } else if (idx < 2 * NW + N3H) {
    int i2 = idx - 2 * NW;
    bx8[i2] = (int8_t)rneclamp(bx[i2] * 256.0f);
  } else if (idx < 2 * NW + 2 * N3H) {
    int i2 = idx - 2 * NW - N3H;
    br8[i2] = (int8_t)rneclamp(br[i2] * 256.0f);
  }
}

// ---------------------------------------------------------------------------
// gemm_wx: Wx_q[b][t][j] = clamp(rne( (fq(x) . Wq col j) / 256 ))  (int8)
// one block per t (64 rows), 768 threads = one per output column.
// ---------------------------------------------------------------------------
__global__ __launch_bounds__(768, 1) void gemm_wx_kernel(
    const float* __restrict__ x, const int8_t* __restrict__ Wq,
    int8_t* __restrict__ WxQ8) {
  const int t = blockIdx.x;   // 0..511
  const int j = threadIdx.x;  // 0..767

  __shared__ uint4 xq4[64 * 16];   // 64 rows x 256 int8 = 16KB
  uint32_t* xq = (uint32_t*)xq4;

  uint4 w[16];
  const uint4* wp = (const uint4*)Wq;
  #pragma unroll
  for (int kk = 0; kk < 16; ++kk) w[kk] = wp[kk * N3H + j];

  const float4* xg = (const float4*)(x) + (size_t)t * 4096;
  for (int i = j; i < 4096; i += 768) {
    float4 f = xg[i];
    xq[i] = packq4(f, 128.0f);
  }
  __syncthreads();

  for (int r = 0; r < 64; ++r) {
    int s = 0;
    #pragma unroll
    for (int kk = 0; kk < 16; ++kk) {
      uint4 hv = xq4[r * 16 + kk];
      s = DOT4(hv.x, w[kk].x, s);
      s = DOT4(hv.y, w[kk].y, s);
      s = DOT4(hv.z, w[kk].z, s);
      s = DOT4(hv.w, w[kk].w, s);
    }
    int q = clamp8(rne_s8(s));
    WxQ8[((size_t)r * T_STEPS + t) * N3H + j] = (int8_t)q;
  }
}

// ---------------------------------------------------------------------------
// gru_rec10: one block per batch; 512 threads = 8 waves, role-split.
//   waves 0-3 (tid<256):  z-col + r-col (128 dw) -> vz,vr -> zi,ri -> LDS
//   waves 4-7 (tid>=256): g-col (64 dw) -> vg; after barrier: gates, h update
// ---------------------------------------------------------------------------
__global__ __launch_bounds__(512) __attribute__((amdgpu_waves_per_eu(2, 2)))
void gru_rec10_kernel(
    const float* __restrict__ h0, const int8_t* __restrict__ Rq,
    const int8_t* __restrict__ bx8, const int8_t* __restrict__ br8,
    const int8_t* __restrict__ WxQ8, float* __restrict__ out) {
  const int b = blockIdx.x;     // batch element
  const int tid = threadIdx.x;  // 0..511
  const int j = tid & 255;      // h / column index
  const int lane = tid & 63;

  __shared__ uint32_t hq[2][64];    // double-buffered int8 h (256 B each)
  __shared__ int zirl[256];         // zi | (ri<<16), both in [0,127]
  __shared__ int8_t lutS[256];
  __shared__ int8_t lutT[256];

  // prologue: LUTs (f64) + initial hq
  {
    double a = ((double)j - 128.0) / 128.0;
    if (tid < 256) {
      lutS[j] = (int8_t)min(127, max(-128, (int)rint(128.0 / (1.0 + exp(-a)))));
    } else {
      lutT[j] = (int8_t)min(127, max(-128, (int)rint(128.0 * tanh(a))));
      int h00 = (int)rintf(h0[b * HDIM + j] * 128.0f);
      ((int8_t*)&hq[0][0])[j] = (int8_t)clamp8(h00);
    }
  }
  __syncthreads();

  if (tid < 256) {
    // ===================== Z/R role =====================
    uint4 wz[16], wr[16];
    {
      const uint4* pz = (const uint4*)(Rq + (size_t)j * HDIM);
      const uint4* pr = (const uint4*)(Rq + (size_t)(j + 256) * HDIM);
      #pragma unroll
      for (int kk = 0; kk < 16; ++kk) { wz[kk] = pz[kk]; wr[kk] = pr[kk]; }
    }
    const int bz  = (int)bx8[j];
    const int brg = (int)bx8[j + 256];
    const int vbz = (int)br8[j];
    const int vbr = (int)br8[j + 256];
    const int8_t* wxp = WxQ8 + (size_t)b * T_STEPS * N3H + j;

    int zA = (int)wxp[0],   rA = (int)wxp[256];
    int zB = (int)wxp[N3H], rB = (int)wxp[N3H + 256];

    for (int t = 0; t < T_STEPS; ++t) {
      const int cur = t & 1;
      const int8_t* p = wxp + (size_t)min(t + 2, T_STEPS - 1) * N3H;
      int zn = (int)p[0], rn = (int)p[256];

      uint32_t hw = hq[cur][lane];
      int sz = 0, sr = 0;
      #pragma unroll
      for (int c = 0; c < 64; ++c) {
        int hc = __builtin_amdgcn_readlane((int)hw, c);
        sz = DOT4(hc, CHUNK(wz, c), sz);
        sr = DOT4(hc, CHUNK(wr, c), sr);
      }
      int vz = clamp8(rne_half(2 * clamp8(rne_s8(sz)) + vbz));
      int vr = clamp8(rne_half(2 * clamp8(rne_s8(sr)) + vbr));
      int az = clamp8(rne_half(2 * (zA + vz) + bz));
      int zi = (int)lutS[az + 128];            // [0,127]
      int ar = clamp8(rne_half(2 * (rA + vr) + brg));
      int ri = (int)lutS[ar + 128];            // [0,127]
      zirl[j] = zi | (ri << 16);

      zA = zB; rA = rB; zB = zn; rB = rn;

      barrier_lds();   // #1: zirl visible to G waves
      barrier_lds();   // #2: hq[nxt] written by G waves
    }
  } else {
    // ===================== G role =====================
    uint4 wg[16];
    {
      const uint4* pg = (const uint4*)(Rq + (size_t)(j + 512) * HDIM);
      #pragma unroll
      for (int kk = 0; kk < 16; ++kk) wg[kk] = pg[kk];
    }
    const int bg  = (int)bx8[j + 512];
    const int vbg = (int)br8[j + 512];
    int hi = (int)rintf(h0[b * HDIM + j] * 128.0f);   // exact int, units 1/128
    const int8_t* wxp = WxQ8 + (size_t)b * T_STEPS * N3H + j + 512;
    float* outp = out + (size_t)b * HDIM + j;

    int gA = (int)wxp[0], gB = (int)wxp[N3H];

    for (int t = 0; t < T_STEPS; ++t) {
      const int cur = t & 1, nxt = cur ^ 1;
      const int8_t* p = wxp + (size_t)min(t + 2, T_STEPS - 1) * N3H;
      int gn = (int)p[0];

      uint32_t hw = hq[cur][lane];
      int sg = 0;
      #pragma unroll
      for (int c = 0; c < 64; ++c) {
        int hc = __builtin_amdgcn_readlane((int)hw, c);
        sg = DOT4(hc, CHUNK(wg, c), sg);
      }
      int vg = clamp8(rne_half(2 * clamp8(rne_s8(sg)) + vbg));

      barrier_lds();   // #1: zirl ready
      int zr_ = zirl[j];
      int zi = zr_ & 0xffff;
      int ri = zr_ >> 16;
      int rrh = clamp8(rne_s7(ri * vg));
      int ag = clamp8(rne_half(2 * (gA + rrh) + bg));
      int gi = (int)lutT[ag + 128];
      int oldi = clamp8(rne_s7(zi * hi));
      int newi = clamp8(rne_s7((128 - zi) * gi));
      hi = oldi + newi;                       // integer, units 1/128
      outp[(size_t)t * BATCH * HDIM] = (float)hi * (1.0f / 128.0f);
      ((int8_t*)&hq[nxt][0])[j] = (int8_t)clamp8(hi);

      gA = gB; gB = gn;

      barrier_lds();   // #2: hq[nxt] published
    }
  }
}

// ---------------------------------------------------------------------------
extern "C" void kernel_launch(void* const* d_in, const int* in_sizes, int n_in,
                              void* d_out, int out_size, void* d_ws, size_t ws_size,
                              hipStream_t stream) {
  const float* x  = (const float*)d_in[0];   // (T,B,I)
  const float* h0 = (const float*)d_in[1];   // (B,H)
  const float* W  = (const float*)d_in[2];   // (I,3H)
  const float* R  = (const float*)d_in[3];   // (H,3H)
  const float* bx = (const float*)d_in[4];   // (3H,)
  const float* br = (const float*)d_in[5];   // (3H,)
  float* out = (float*)d_out;                // (T,B,H)

  // workspace layout
  const size_t NW = (size_t)IDIM * N3H;          // 196608
  int8_t* Wq  = (int8_t*)d_ws;                   // 196608
  int8_t* Rq  = Wq + NW;                         // 196608
  int8_t* bx8 = Rq + NW;                         // 768
  int8_t* br8 = bx8 + N3H;                       // 768
  int8_t* WxQ8 = br8 + N3H;                      // 64*512*768 = 25165824

  {
    int total = (int)(2 * NW + 2 * N3H);
    int blocks = (total + 255) / 256;
    prep_kernel<<<blocks, 256, 0, stream>>>(W, R, bx, br, Wq, Rq, bx8, br8);
  }
  gemm_wx_kernel<<<T_STEPS, 768, 0, stream>>>(x, Wq, WxQ8);
  gru_rec10_kernel<<<BATCH, 512, 0, stream>>>(h0, Rq, bx8, br8, WxQ8, out);
}